// Round 9
// baseline (1995.119 us; speedup 1.0000x reference)
//
#include <hip/hip_runtime.h>
#include <hip/hip_bf16.h>

// LatentSensorMoE: fused bf16-MFMA expert MLPs + fp32 gate path, single main dispatch.
// B=32768, EIN=128, E=8, experts 128->512->256->128->1 (LN+SiLU per hidden),
// gate: 64->128(LN,SiLU)->128(LN,SiLU); enc 128->64(SiLU)->16; gating 144->128(LN,SiLU)->64(SiLU)->8->softmax.
// Outputs (fp32, concat): mixed[B] | z[B,16] | logits[B,8] | gates[B,8]
//
// R9 = R6 exact skeleton (passing, 435us: pack_x+Xp, gate LAST at y==8, 2D grid) +
// (a) gate W staged through LDS in 32-k chunks using the dead output buffer as the
// chunk buffer (cuts the gate tail's L2 traffic ~8x; bitwise-identical math),
// (b) pack_x merged into the pack dispatch (one kernel, 2948 blocks).
// Quarantined (HW-failure evidence): direct-X stage-1 (R7/R8), gate-not-last
// scheduling (R7/R8), flat f%9 interleave (R7), bias-post-loop epilogue + 16-row
// gate (R3/R4).

typedef __attribute__((ext_vector_type(8))) short bf16x8;   // 8 bf16 = 4 VGPR (MFMA frag)
typedef __attribute__((ext_vector_type(4))) float f32x4;

#define DEV static __device__ __forceinline__

DEV float b2f(unsigned short u){ union { unsigned int i; float f; } x; x.i = ((unsigned int)u) << 16; return x.f; }
DEV unsigned short f2b(float f){
  union { float f; unsigned int i; } x; x.f = f;
  return (unsigned short)((x.i + 0x7fffu + ((x.i >> 16) & 1u)) >> 16);  // RNE
}
DEV unsigned int pk2(float a, float b){
  __hip_bfloat162 h = __float22bfloat162_rn(make_float2(a, b));        // v_cvt_pk_bf16_f32
  union { __hip_bfloat162 h; unsigned int u; } u; u.h = h; return u.u;
}
// silu via fast rcp (v_rcp_f32, ~5 VALU) instead of IEEE div sequence (~10 VALU)
DEV float silu_f(float v){ return v * __builtin_amdgcn_rcpf(1.0f + __expf(-v)); }

// ---------------- pack kernel: X + weights fp32 -> bf16 MFMA fragment layouts ----------------
// A-frag (16x16x32): lane l holds A[m=l&15][k=(l>>4)*8+j], j=0..7
// B-frag:            lane l holds B[k=(l>>4)*8+j][n=l&15]
// Stage s output is written to LDS in permuted k' order; W(s+1) k-dim pre-permuted to match:
//  pi1: col c=(w*128+nt*16+c0) -> k' = w*128 + c0*8 + nt   (nt<8)
//  pi2: col c=(w*64 +nt*16+c0) -> k' = w*64  + c0*4 + nt   (nt<4)
//  pi3: col c=(w*32 +nt*16+c0) -> k' = w*32  + c0*2 + nt   (nt<2)
// blocks [0,256)=W1, [256,768)=W2, [768,896)=W3, [896,900)=w4, [900,2948)=X
__global__ __launch_bounds__(256) void pack_all_kernel(const float* __restrict__ eW1, const float* __restrict__ eW2,
                                                       const float* __restrict__ eW3, const float* __restrict__ eW4,
                                                       const float* __restrict__ X,
                                                       unsigned short* __restrict__ W1p, unsigned short* __restrict__ W2p,
                                                       unsigned short* __restrict__ W3p, float* __restrict__ w4p,
                                                       unsigned short* __restrict__ Xp){
  int b = blockIdx.x;
  if (b < 256){
    int t = b * 256 + threadIdx.x;                 // [0, 65536)
    int l = t & 63, kb = (t >> 6) & 3, ntg = (t >> 8) & 31, e = t >> 13;
    int q = l >> 4, c0 = l & 15, n = ntg * 16 + c0;
    bf16x8 o;
    #pragma unroll
    for (int j = 0; j < 8; j++){ int k = kb*32 + q*8 + j; o[j] = (short)f2b(eW1[((size_t)e*128 + k)*512 + n]); }
    *(bf16x8*)(W1p + (size_t)t * 8) = o;
  } else if (b < 768){
    int t = (b - 256) * 256 + threadIdx.x;         // [0, 131072)
    int l = t & 63, kb = (t >> 6) & 15, ntg = (t >> 10) & 15, e = t >> 14;
    int q = l >> 4, c0 = l & 15, n = ntg * 16 + c0;
    bf16x8 o;
    #pragma unroll
    for (int j = 0; j < 8; j++){
      int kp = kb*32 + q*8 + j;                                        // k' in pi1 space
      int c = (kp >> 7) * 128 + (kp & 7) * 16 + ((kp >> 3) & 15);      // pi1^-1
      o[j] = (short)f2b(eW2[((size_t)e*512 + c)*256 + n]);
    }
    *(bf16x8*)(W2p + (size_t)t * 8) = o;
  } else if (b < 896){
    int t = (b - 768) * 256 + threadIdx.x;         // [0, 32768)
    int l = t & 63, kb = (t >> 6) & 7, ntg = (t >> 9) & 7, e = t >> 12;
    int q = l >> 4, c0 = l & 15, n = ntg * 16 + c0;
    bf16x8 o;
    #pragma unroll
    for (int j = 0; j < 8; j++){
      int kp = kb*32 + q*8 + j;                                        // k' in pi2 space
      int c = (kp >> 6) * 64 + (kp & 3) * 16 + ((kp >> 2) & 15);       // pi2^-1
      o[j] = (short)f2b(eW3[((size_t)e*256 + c)*128 + n]);
    }
    *(bf16x8*)(W3p + (size_t)t * 8) = o;
  } else if (b < 900){
    int t = (b - 896) * 256 + threadIdx.x;
    if (t < 1024){
      int e = t >> 7, kp = t & 127;
      int c = (kp >> 5) * 32 + (kp & 1) * 16 + ((kp >> 1) & 15);       // pi3^-1
      w4p[t] = eW4[e * 128 + c];
    }
  } else {
    int t = (b - 900) * 256 + threadIdx.x;         // [0, 524288)
    int l = t & 63, kb = (t >> 6) & 3, mtg = t >> 8; // mtg: 16-row tile id [0,2048)
    int row = mtg * 16 + (l & 15);
    int k0  = kb * 32 + (l >> 4) * 8;
    const float* src = X + (size_t)row * 128 + k0;
    bf16x8 o;
    #pragma unroll
    for (int j = 0; j < 8; j++) o[j] = (short)f2b(src[j]);
    *(bf16x8*)(Xp + (size_t)t * 8) = o;
  }
}

// ---------------- gate layers: W staged through LDS (chunk buffer = dead ys) ----------------
// N=128 layer: thread tile 4 rows x 4 cols. W chunks of 32 k-rows (16.9KB at pitch 132)
// are cooperatively loaded into ys (dead until the epilogue), cutting per-block L2
// W-traffic 8x. Math is bitwise identical to the unstaged version.
template<int K, int PIN, int POUT, bool LN>
DEV void glayer128(const float* __restrict__ xs, const float* __restrict__ W, const float* __restrict__ b,
                   const float* __restrict__ g, const float* __restrict__ btv, float* __restrict__ ys, int tid)
{
  const int cg = tid & 31, rg = tid >> 5;
  const int col0 = cg * 4, row0 = rg * 4;
  float* wbuf = ys;                                // 32*132 floats <= 32*POUT (POUT>=132)
  float4 bv = *(const float4*)(b + col0);
  float acc[4][4];
  #pragma unroll
  for (int r = 0; r < 4; r++){ acc[r][0] = bv.x; acc[r][1] = bv.y; acc[r][2] = bv.z; acc[r][3] = bv.w; }
  for (int k0 = 0; k0 < K; k0 += 32){
    const int kc = (K - k0 < 32) ? (K - k0) : 32;
    __syncthreads();                               // prior chunk fully consumed
    for (int idx = tid; idx < kc*32; idx += 256){
      int kk = idx >> 5, c4 = (idx & 31) * 4;
      *(float4*)(wbuf + kk*132 + c4) = *(const float4*)(W + (size_t)(k0+kk)*128 + c4);
    }
    __syncthreads();
    for (int kk = 0; kk < kc; kk += 4){
      float4 x0 = *(const float4*)(xs + (row0+0)*PIN + k0+kk);
      float4 x1 = *(const float4*)(xs + (row0+1)*PIN + k0+kk);
      float4 x2 = *(const float4*)(xs + (row0+2)*PIN + k0+kk);
      float4 x3 = *(const float4*)(xs + (row0+3)*PIN + k0+kk);
      float4 w0 = *(const float4*)(wbuf + (kk+0)*132 + col0);
      float4 w1 = *(const float4*)(wbuf + (kk+1)*132 + col0);
      float4 w2 = *(const float4*)(wbuf + (kk+2)*132 + col0);
      float4 w3 = *(const float4*)(wbuf + (kk+3)*132 + col0);
      const float xr[4][4] = {{x0.x,x0.y,x0.z,x0.w},{x1.x,x1.y,x1.z,x1.w},{x2.x,x2.y,x2.z,x2.w},{x3.x,x3.y,x3.z,x3.w}};
      const float wr[4][4] = {{w0.x,w0.y,w0.z,w0.w},{w1.x,w1.y,w1.z,w1.w},{w2.x,w2.y,w2.z,w2.w},{w3.x,w3.y,w3.z,w3.w}};
      #pragma unroll
      for (int kq = 0; kq < 4; kq++)
        #pragma unroll
        for (int r = 0; r < 4; r++)
          #pragma unroll
          for (int c = 0; c < 4; c++) acc[r][c] += xr[r][kq] * wr[kq][c];
    }
  }
  __syncthreads();                                 // last chunk consumed -> ys reusable
  float mu[4], rs[4];
  if (LN){
    #pragma unroll
    for (int r = 0; r < 4; r++){
      float s = acc[r][0] + acc[r][1] + acc[r][2] + acc[r][3];
      float qq = acc[r][0]*acc[r][0] + acc[r][1]*acc[r][1] + acc[r][2]*acc[r][2] + acc[r][3]*acc[r][3];
      #pragma unroll
      for (int off = 1; off < 32; off <<= 1){ s += __shfl_xor(s, off, 64); qq += __shfl_xor(qq, off, 64); }
      float m = s * (1.0f/128.0f);
      mu[r] = m; rs[r] = rsqrtf(qq * (1.0f/128.0f) - m*m + 1e-5f);
    }
    float4 gv = *(const float4*)(g + col0);
    float4 tv = *(const float4*)(btv + col0);
    const float gr[4] = {gv.x, gv.y, gv.z, gv.w};
    const float tr[4] = {tv.x, tv.y, tv.z, tv.w};
    #pragma unroll
    for (int r = 0; r < 4; r++)
      #pragma unroll
      for (int c = 0; c < 4; c++) acc[r][c] = (acc[r][c] - mu[r]) * rs[r] * gr[c] + tr[c];
  }
  #pragma unroll
  for (int r = 0; r < 4; r++){
    float4 o;
    o.x = silu_f(acc[r][0]); o.y = silu_f(acc[r][1]); o.z = silu_f(acc[r][2]); o.w = silu_f(acc[r][3]);
    *(float4*)(ys + (row0+r)*POUT + col0) = o;
  }
}

// N=64, SiLU only: thread tile 2 rows x 4 cols; W chunks at pitch 68 (2176 floats <= 32*POUT)
template<int K, int PIN, int POUT>
DEV void glayer64(const float* __restrict__ xs, const float* __restrict__ W, const float* __restrict__ b,
                  float* __restrict__ ys, int tid)
{
  const int cg = tid & 15, rg = tid >> 4;
  const int col0 = cg * 4, row0 = rg * 2;
  float* wbuf = ys;
  float4 bv = *(const float4*)(b + col0);
  float acc[2][4];
  #pragma unroll
  for (int r = 0; r < 2; r++){ acc[r][0] = bv.x; acc[r][1] = bv.y; acc[r][2] = bv.z; acc[r][3] = bv.w; }
  for (int k0 = 0; k0 < K; k0 += 32){
    const int kc = (K - k0 < 32) ? (K - k0) : 32;
    __syncthreads();
    for (int idx = tid; idx < kc*16; idx += 256){
      int kk = idx >> 4, c4 = (idx & 15) * 4;
      *(float4*)(wbuf + kk*68 + c4) = *(const float4*)(W + (size_t)(k0+kk)*64 + c4);
    }
    __syncthreads();
    for (int kk = 0; kk < kc; kk += 4){
      float4 x0 = *(const float4*)(xs + (row0+0)*PIN + k0+kk);
      float4 x1 = *(const float4*)(xs + (row0+1)*PIN + k0+kk);
      float4 w0 = *(const float4*)(wbuf + (kk+0)*68 + col0);
      float4 w1 = *(const float4*)(wbuf + (kk+1)*68 + col0);
      float4 w2 = *(const float4*)(wbuf + (kk+2)*68 + col0);
      float4 w3 = *(const float4*)(wbuf + (kk+3)*68 + col0);
      const float xr[2][4] = {{x0.x,x0.y,x0.z,x0.w},{x1.x,x1.y,x1.z,x1.w}};
      const float wr[4][4] = {{w0.x,w0.y,w0.z,w0.w},{w1.x,w1.y,w1.z,w1.w},{w2.x,w2.y,w2.z,w2.w},{w3.x,w3.y,w3.z,w3.w}};
      #pragma unroll
      for (int kq = 0; kq < 4; kq++)
        #pragma unroll
        for (int r = 0; r < 2; r++)
          #pragma unroll
          for (int c = 0; c < 4; c++) acc[r][c] += xr[r][kq] * wr[kq][c];
    }
  }
  __syncthreads();                                 // last chunk consumed -> ys reusable
  #pragma unroll
  for (int r = 0; r < 2; r++){
    float4 o;
    o.x = silu_f(acc[r][0]); o.y = silu_f(acc[r][1]); o.z = silu_f(acc[r][2]); o.w = silu_f(acc[r][3]);
    *(float4*)(ys + (row0+r)*POUT + col0) = o;
  }
}

DEV void gate_body(unsigned char* smem, int bx, int tid,
                   const float* __restrict__ gf,
                   const float* __restrict__ bW1, const float* __restrict__ bb1, const float* __restrict__ bg1, const float* __restrict__ bbt1,
                   const float* __restrict__ bW2, const float* __restrict__ bb2, const float* __restrict__ bg2, const float* __restrict__ bbt2,
                   const float* __restrict__ encW1, const float* __restrict__ encb1, const float* __restrict__ encW2, const float* __restrict__ encb2,
                   const float* __restrict__ gW1, const float* __restrict__ gb1, const float* __restrict__ gg1v, const float* __restrict__ gbt1,
                   const float* __restrict__ gW2, const float* __restrict__ gb2, const float* __restrict__ gW3, const float* __restrict__ gb3,
                   float* __restrict__ out_z, float* __restrict__ out_logits, float* __restrict__ out_gates)
{
  const int row0 = bx * 32;
  float* xa = (float*)smem;                  // [0, 18944) B : 32*148 floats
  float* xb = (float*)(smem + 18944);        // [18944, 35840) B : 32*132 floats

  // load gate_features [32,64]
  for (int idx = tid; idx < 32*64; idx += 256){
    int r = idx >> 6, k = idx & 63;
    xa[r*148 + k] = gf[(size_t)(row0 + r)*64 + k];
  }
  __syncthreads();
  glayer128<64, 148, 132, true>(xa, bW1, bb1, bg1, bbt1, xb, tid);     // h1 -> xb
  __syncthreads();
  glayer128<128, 132, 148, true>(xb, bW2, bb2, bg2, bbt2, xa, tid);    // h2 -> xa[0..127]
  __syncthreads();
  glayer64<128, 148, 132>(xa, encW1, encb1, xb, tid);                  // enc1 -> xb[0..63]
  __syncthreads();
  { // enc2: xb[32,64] @ encW2[64,16] -> z; write out_z and xa cols 128..143
    int col = tid & 15, rr = tid >> 4;           // rr 0..15 -> rows rr*2, rr*2+1
    float a0 = encb2[col], a1 = a0;
    for (int k = 0; k < 64; k++){
      float wv = encW2[k*16 + col];
      a0 += xb[(rr*2+0)*132 + k] * wv;
      a1 += xb[(rr*2+1)*132 + k] * wv;
    }
    out_z[(size_t)(row0 + rr*2+0)*16 + col] = a0;
    out_z[(size_t)(row0 + rr*2+1)*16 + col] = a1;
    xa[(rr*2+0)*148 + 128 + col] = a0;
    xa[(rr*2+1)*148 + 128 + col] = a1;
  }
  __syncthreads();
  glayer128<144, 148, 132, true>(xa, gW1, gb1, gg1v, gbt1, xb, tid);   // gating h -> xb
  __syncthreads();
  glayer64<128, 132, 148>(xb, gW2, gb2, xa, tid);                      // -> xa[0..63]
  __syncthreads();
  { // g3: xa[32,64] @ gW3[64,8] -> logits; softmax -> gates
    int col = tid & 7, rr = tid >> 3;            // rr 0..31
    float a = gb3[col];
    for (int k = 0; k < 64; k++) a += xa[rr*148 + k] * gW3[k*8 + col];
    out_logits[(size_t)(row0 + rr)*8 + col] = a;
    float m = a;
    m = fmaxf(m, __shfl_xor(m, 1, 64));
    m = fmaxf(m, __shfl_xor(m, 2, 64));
    m = fmaxf(m, __shfl_xor(m, 4, 64));
    float ex = __expf(a - m);
    float s = ex;
    s += __shfl_xor(s, 1, 64); s += __shfl_xor(s, 2, 64); s += __shfl_xor(s, 4, 64);
    out_gates[(size_t)(row0 + rr)*8 + col] = ex / s;
  }
}

// ---------------- main fused dispatch: grid (1024, 9) ----------------
// blockIdx.y < 8 : expert body (32 rows x expert y). blockIdx.y == 8 : gate body
// (dispatches last — the R6-proven schedule).
// LDS: one 35840B carve-out unioned across both bodies -> 4 blocks/CU at (256,4).
#define MFMA_BF16 __builtin_amdgcn_mfma_f32_16x16x32_bf16

__global__ __launch_bounds__(256, 4)
void fused_main(const unsigned short* __restrict__ Xp,
                const unsigned short* __restrict__ W1p,
                const unsigned short* __restrict__ W2p,
                const unsigned short* __restrict__ W3p,
                const float* __restrict__ w4p,
                const float* __restrict__ eb1, const float* __restrict__ eg1, const float* __restrict__ ebt1,
                const float* __restrict__ eb2, const float* __restrict__ eg2, const float* __restrict__ ebt2,
                const float* __restrict__ eb3, const float* __restrict__ eg3, const float* __restrict__ ebt3,
                const float* __restrict__ eb4, float* __restrict__ eo,
                const float* __restrict__ gf,
                const float* __restrict__ bW1, const float* __restrict__ bb1, const float* __restrict__ bg1, const float* __restrict__ bbt1,
                const float* __restrict__ bW2, const float* __restrict__ bb2, const float* __restrict__ bg2, const float* __restrict__ bbt2,
                const float* __restrict__ encW1, const float* __restrict__ encb1, const float* __restrict__ encW2, const float* __restrict__ encb2,
                const float* __restrict__ gW1, const float* __restrict__ gb1, const float* __restrict__ gg1v, const float* __restrict__ gbt1,
                const float* __restrict__ gW2, const float* __restrict__ gb2, const float* __restrict__ gW3, const float* __restrict__ gb3,
                float* __restrict__ out_z, float* __restrict__ out_logits, float* __restrict__ out_gates)
{
  __shared__ __align__(16) unsigned char smem[35840];
  const int tid = threadIdx.x;

  if (blockIdx.y == 8){
    gate_body(smem, blockIdx.x, tid, gf,
              bW1, bb1, bg1, bbt1, bW2, bb2, bg2, bbt2,
              encW1, encb1, encW2, encb2,
              gW1, gb1, gg1v, gbt1, gW2, gb2, gW3, gb3,
              out_z, out_logits, out_gates);
    return;
  }

  const int e = blockIdx.y, bt = blockIdx.x;
  const int w = tid >> 6, l = tid & 63;
  const int q = l >> 4, c0 = l & 15;

  unsigned short* h1 = (unsigned short*)smem;          // [0, 33280) B
  float* redS = (float*)(smem + 33280);                // 128 floats
  float* redQ = (float*)(smem + 33792);                // 128 floats
  float* muS  = (float*)(smem + 34304);                // 32 floats
  float* rsS  = (float*)(smem + 34432);                // 32 floats
  unsigned short* h2 = h1;                 // [0, 16896) B — h1 dead after stage-2 k-loop barrier
  unsigned short* h3 = h1 + 32 * 264;      // [16896, 25600) B — disjoint from h2

  // ===== stage 1: X[32,128] @ W1[128,512], +b (as C-init), LN, SiLU -> h1 (k' = pi1) =====
  {
    float bv[8], gv[8], tv[8];
    #pragma unroll
    for (int nt = 0; nt < 8; nt++){
      int col = w*128 + nt*16 + c0;
      bv[nt] = eb1[e*512 + col]; gv[nt] = eg1[e*512 + col]; tv[nt] = ebt1[e*512 + col];
    }
    f32x4 acc[2][8];
    #pragma unroll
    for (int m = 0; m < 2; m++)
      #pragma unroll
      for (int nt = 0; nt < 8; nt++) acc[m][nt] = (f32x4){bv[nt],bv[nt],bv[nt],bv[nt]};
    #pragma unroll
    for (int kb = 0; kb < 4; kb++){
      bf16x8 a0 = *(const bf16x8*)(Xp + ((size_t)((bt*2 + 0)*4 + kb)*64 + l)*8);
      bf16x8 a1 = *(const bf16x8*)(Xp + ((size_t)((bt*2 + 1)*4 + kb)*64 + l)*8);
      #pragma unroll
      for (int nt = 0; nt < 8; nt++){
        int ntg = w*8 + nt;
        bf16x8 b = *(const bf16x8*)(W1p + ((size_t)((e*32 + ntg)*4 + kb)*64 + l)*8);
        acc[0][nt] = MFMA_BF16(a0, b, acc[0][nt], 0, 0, 0);
        acc[1][nt] = MFMA_BF16(a1, b, acc[1][nt], 0, 0, 0);
      }
    }
    float s[2][4] = {}, sq[2][4] = {};
    #pragma unroll
    for (int nt = 0; nt < 8; nt++)
      #pragma unroll
      for (int m = 0; m < 2; m++)
        #pragma unroll
        for (int r = 0; r < 4; r++){
          float v = acc[m][nt][r];
          s[m][r] += v; sq[m][r] += v*v;
        }
    #pragma unroll
    for (int m = 0; m < 2; m++)
      #pragma unroll
      for (int r = 0; r < 4; r++){
        float a = s[m][r], b = sq[m][r];
        #pragma unroll
        for (int off = 1; off < 16; off <<= 1){ a += __shfl_xor(a, off, 64); b += __shfl_xor(b, off, 64); }
        if (c0 == 0){ int row = m*16 + q*4 + r; redS[row*4 + w] = a; redQ[row*4 + w] = b; }
      }
    __syncthreads();
    if (tid < 32){
      float S = 0.f, Q = 0.f;
      #pragma unroll
      for (int i = 0; i < 4; i++){ S += redS[tid*4 + i]; Q += redQ[tid*4 + i]; }
      float mu = S * (1.0f/512.0f);
      float var = Q * (1.0f/512.0f) - mu*mu;
      muS[tid] = mu; rsS[tid] = rsqrtf(var + 1e-5f);
    }
    __syncthreads();
    #pragma unroll
    for (int m = 0; m < 2; m++)
      #pragma unroll
      for (int r = 0; r < 4; r++){
        int row = m*16 + q*4 + r;
        float mu = muS[row], rs = rsS[row];
        float v[8];
        #pragma unroll
        for (int nt = 0; nt < 8; nt++) v[nt] = silu_f((acc[m][nt][r] - mu) * rs * gv[nt] + tv[nt]);
        uint4 pk;
        pk.x = pk2(v[0], v[1]); pk.y = pk2(v[2], v[3]); pk.z = pk2(v[4], v[5]); pk.w = pk2(v[6], v[7]);
        *(uint4*)(h1 + row*520 + w*128 + c0*8) = pk;   // ds_write_b128, k' = w*128+c0*8+nt
      }
  }
  __syncthreads();

  // ===== stage 2: h1[32,512(pi1)] @ W2p, +b, LN, SiLU -> h2 (k' = pi2, aliases h1) =====
  {
    float bv[4], gv[4], tv[4];
    #pragma unroll
    for (int nt = 0; nt < 4; nt++){
      int col = w*64 + nt*16 + c0;
      bv[nt] = eb2[e*256 + col]; gv[nt] = eg2[e*256 + col]; tv[nt] = ebt2[e*256 + col];
    }
    f32x4 acc[2][4];
    #pragma unroll
    for (int m = 0; m < 2; m++)
      #pragma unroll
      for (int nt = 0; nt < 4; nt++) acc[m][nt] = (f32x4){bv[nt],bv[nt],bv[nt],bv[nt]};
    #pragma unroll 2
    for (int kb = 0; kb < 16; kb++){
      bf16x8 a0 = *(const bf16x8*)(h1 + (0  + c0)*520 + kb*32 + q*8);
      bf16x8 a1 = *(const bf16x8*)(h1 + (16 + c0)*520 + kb*32 + q*8);
      #pragma unroll
      for (int nt = 0; nt < 4; nt++){
        int ntg = w*4 + nt;
        bf16x8 b = *(const bf16x8*)(W2p + ((size_t)((e*16 + ntg)*16 + kb)*64 + l)*8);
        acc[0][nt] = MFMA_BF16(a0, b, acc[0][nt], 0, 0, 0);
        acc[1][nt] = MFMA_BF16(a1, b, acc[1][nt], 0, 0, 0);
      }
    }
    float s[2][4] = {}, sq[2][4] = {};
    #pragma unroll
    for (int nt = 0; nt < 4; nt++)
      #pragma unroll
      for (int m = 0; m < 2; m++)
        #pragma unroll
        for (int r = 0; r < 4; r++){
          float v = acc[m][nt][r];
          s[m][r] += v; sq[m][r] += v*v;
        }
    #pragma unroll
    for (int m = 0; m < 2; m++)
      #pragma unroll
      for (int r = 0; r < 4; r++){
        float a = s[m][r], b = sq[m][r];
        #pragma unroll
        for (int off = 1; off < 16; off <<= 1){ a += __shfl_xor(a, off, 64); b += __shfl_xor(b, off, 64); }
        if (c0 == 0){ int row = m*16 + q*4 + r; redS[row*4 + w] = a; redQ[row*4 + w] = b; }
      }
    __syncthreads();   // all stage-2 k-loop reads of h1 complete here -> h2 may overwrite h1
    if (tid < 32){
      float S = 0.f, Q = 0.f;
      #pragma unroll
      for (int i = 0; i < 4; i++){ S += redS[tid*4 + i]; Q += redQ[tid*4 + i]; }
      float mu = S * (1.0f/256.0f);
      float var = Q * (1.0f/256.0f) - mu*mu;
      muS[tid] = mu; rsS[tid] = rsqrtf(var + 1e-5f);
    }
    __syncthreads();
    #pragma unroll
    for (int m = 0; m < 2; m++)
      #pragma unroll
      for (int r = 0; r < 4; r++){
        int row = m*16 + q*4 + r;
        float mu = muS[row], rs = rsS[row];
        float v[4];
        #pragma unroll
        for (int nt = 0; nt < 4; nt++) v[nt] = silu_f((acc[m][nt][r] - mu) * rs * gv[nt] + tv[nt]);
        uint2 pk; pk.x = pk2(v[0], v[1]); pk.y = pk2(v[2], v[3]);
        *(uint2*)(h2 + row*264 + w*64 + c0*4) = pk;    // ds_write_b64, k' = w*64+c0*4+nt
      }
  }
  __syncthreads();

  // ===== stage 3: h2[32,256(pi2)] @ W3p, +b, LN, SiLU -> h3 (k' = pi3) =====
  {
    float bv[2], gv[2], tv[2];
    #pragma unroll
    for (int nt = 0; nt < 2; nt++){
      int col = w*32 + nt*16 + c0;
      bv[nt] = eb3[e*128 + col]; gv[nt] = eg3[e*128 + col]; tv[nt] = ebt3[e*128 + col];
    }
    f32x4 acc[2][2];
    #pragma unroll
    for (int m = 0; m < 2; m++)
      #pragma unroll
      for (int nt = 0; nt < 2; nt++) acc[m][nt] = (f32x4){bv[nt],bv[nt],bv[nt],bv[nt]};
    #pragma unroll 2
    for (int kb = 0; kb < 8; kb++){
      bf16x8 a0 = *(const bf16x8*)(h2 + (0  + c0)*264 + kb*32 + q*8);
      bf16x8 a1 = *(const bf16x8*)(h2 + (16 + c0)*264 + kb*32 + q*8);
      #pragma unroll
      for (int nt = 0; nt < 2; nt++){
        int ntg = w*2 + nt;
        bf16x8 b = *(const bf16x8*)(W3p + ((size_t)((e*8 + ntg)*8 + kb)*64 + l)*8);
        acc[0][nt] = MFMA_BF16(a0, b, acc[0][nt], 0, 0, 0);
        acc[1][nt] = MFMA_BF16(a1, b, acc[1][nt], 0, 0, 0);
      }
    }
    float s[2][4] = {}, sq[2][4] = {};
    #pragma unroll
    for (int nt = 0; nt < 2; nt++)
      #pragma unroll
      for (int m = 0; m < 2; m++)
        #pragma unroll
        for (int r = 0; r < 4; r++){
          float v = acc[m][nt][r];
          s[m][r] += v; sq[m][r] += v*v;
        }
    #pragma unroll
    for (int m = 0; m < 2; m++)
      #pragma unroll
      for (int r = 0; r < 4; r++){
        float a = s[m][r], b = sq[m][r];
        #pragma unroll
        for (int off = 1; off < 16; off <<= 1){ a += __shfl_xor(a, off, 64); b += __shfl_xor(b, off, 64); }
        if (c0 == 0){ int row = m*16 + q*4 + r; redS[row*4 + w] = a; redQ[row*4 + w] = b; }
      }
    __syncthreads();   // all stage-3 k-loop reads of h2 complete here
    if (tid < 32){
      float S = 0.f, Q = 0.f;
      #pragma unroll
      for (int i = 0; i < 4; i++){ S += redS[tid*4 + i]; Q += redQ[tid*4 + i]; }
      float mu = S * (1.0f/128.0f);
      float var = Q * (1.0f/128.0f) - mu*mu;
      muS[tid] = mu; rsS[tid] = rsqrtf(var + 1e-5f);
    }
    __syncthreads();
    #pragma unroll
    for (int m = 0; m < 2; m++)
      #pragma unroll
      for (int r = 0; r < 4; r++){
        int row = m*16 + q*4 + r;
        float mu = muS[row], rs = rsS[row];
        float v0 = silu_f((acc[m][0][r] - mu) * rs * gv[0] + tv[0]);
        float v1 = silu_f((acc[m][1][r] - mu) * rs * gv[1] + tv[1]);
        *(unsigned int*)(h3 + row*136 + w*32 + c0*2) = pk2(v0, v1);  // ds_write_b32, k' = w*32+c0*2+nt
      }
  }
  __syncthreads();

  // ===== stage 4: h3[32,128(pi3)] . w4p[e] + eb4 -> eo[b, e] =====
  {
    int row = tid >> 3, sub = tid & 7;
    bf16x8 v0 = *(const bf16x8*)(h3 + row*136 + sub*16);
    bf16x8 v1 = *(const bf16x8*)(h3 + row*136 + sub*16 + 8);
    float a = 0.f;
    #pragma unroll
    for (int j = 0; j < 8; j++) a += b2f((unsigned short)v0[j]) * w4p[e*128 + sub*16 + j];
    #pragma unroll
    for (int j = 0; j < 8; j++) a += b2f((unsigned short)v1[j]) * w4p[e*128 + sub*16 + 8 + j];
    a += __shfl_xor(a, 1, 64); a += __shfl_xor(a, 2, 64); a += __shfl_xor(a, 4, 64);
    if (sub == 0) eo[(size_t)(bt*32 + row)*8 + e] = a + eb4[e];
  }
}

// ---------------- final mix: mixed[b] = sum_e eo[b,e]*gates[b,e] ----------------
__global__ __launch_bounds__(256) void mix_kernel(const float* __restrict__ eo, const float* __restrict__ gates,
                                                  float* __restrict__ mixed){
  int t = blockIdx.x * 256 + threadIdx.x;
  if (t < 32768){
    const float4* a = (const float4*)(eo + (size_t)t*8);
    const float4* gg = (const float4*)(gates + (size_t)t*8);
    float4 a0 = a[0], a1 = a[1], g0 = gg[0], g1 = gg[1];
    mixed[t] = a0.x*g0.x + a0.y*g0.y + a0.z*g0.z + a0.w*g0.w
             + a1.x*g1.x + a1.y*g1.y + a1.z*g1.z + a1.w*g1.w;
  }
}

extern "C" void kernel_launch(void* const* d_in, const int* in_sizes, int n_in,
                              void* d_out, int out_size, void* d_ws, size_t ws_size,
                              hipStream_t stream)
{
  if (n_in < 36 || in_sizes[0] != 32768*128 || out_size < 1081344) return;

  const float* expert_features = (const float*)d_in[0];
  const float* gate_features   = (const float*)d_in[1];
  const float* eW1 = (const float*)d_in[2];
  const float* eb1 = (const float*)d_in[3];
  const float* eg1 = (const float*)d_in[4];
  const float* ebt1= (const float*)d_in[5];
  const float* eW2 = (const float*)d_in[6];
  const float* eb2 = (const float*)d_in[7];
  const float* eg2 = (const float*)d_in[8];
  const float* ebt2= (const float*)d_in[9];
  const float* eW3 = (const float*)d_in[10];
  const float* eb3 = (const float*)d_in[11];
  const float* eg3 = (const float*)d_in[12];
  const float* ebt3= (const float*)d_in[13];
  const float* eW4 = (const float*)d_in[14];
  const float* eb4 = (const float*)d_in[15];
  const float* bW1 = (const float*)d_in[16];
  const float* bb1 = (const float*)d_in[17];
  const float* bg1 = (const float*)d_in[18];
  const float* bbt1= (const float*)d_in[19];
  const float* bW2 = (const float*)d_in[20];
  const float* bb2 = (const float*)d_in[21];
  const float* bg2 = (const float*)d_in[22];
  const float* bbt2= (const float*)d_in[23];
  const float* encW1 = (const float*)d_in[24];
  const float* encb1 = (const float*)d_in[25];
  const float* encW2 = (const float*)d_in[26];
  const float* encb2 = (const float*)d_in[27];
  const float* gW1 = (const float*)d_in[28];
  const float* gb1 = (const float*)d_in[29];
  const float* gg1 = (const float*)d_in[30];
  const float* gbt1= (const float*)d_in[31];
  const float* gW2 = (const float*)d_in[32];
  const float* gb2 = (const float*)d_in[33];
  const float* gW3 = (const float*)d_in[34];
  const float* gb3 = (const float*)d_in[35];

  float* out        = (float*)d_out;
  float* out_mixed  = out;                 // [B]
  float* out_z      = out + 32768;         // [B,16]
  float* out_logits = out + 557056;        // [B,8]
  float* out_gates  = out + 819200;        // [B,8]

  char* ws = (char*)d_ws;
  size_t off = 0;
  auto walloc = [&](size_t bytes) -> char* { char* p = ws + off; off += (bytes + 255) & ~(size_t)255; return p; };
  unsigned short* Xp  = (unsigned short*)walloc((size_t)4194304 * 2);  // packed X, bf16
  unsigned short* W1p = (unsigned short*)walloc((size_t)524288  * 2);
  unsigned short* W2p = (unsigned short*)walloc((size_t)1048576 * 2);
  unsigned short* W3p = (unsigned short*)walloc((size_t)262144  * 2);
  float*          w4p = (float*)walloc((size_t)1024 * 4);
  float*          eo  = (float*)walloc((size_t)262144 * 4);            // expert outputs [B,8]
  if (off > ws_size) return;  // workspace too small -> clean failure signal

  // --- pack X + weights (one dispatch) ---
  pack_all_kernel<<<2948, 256, 0, stream>>>(eW1, eW2, eW3, eW4, expert_features,
                                            W1p, W2p, W3p, w4p, Xp);

  // --- experts (y<8) + gate path (y==8, dispatches last — R6-proven schedule) ---
  fused_main<<<dim3(1024, 9), 256, 0, stream>>>(Xp, W1p, W2p, W3p, w4p,
                                                eb1, eg1, ebt1, eb2, eg2, ebt2, eb3, eg3, ebt3,
                                                eb4, eo,
                                                gate_features,
                                                bW1, bb1, bg1, bbt1, bW2, bb2, bg2, bbt2,
                                                encW1, encb1, encW2, encb2,
                                                gW1, gb1, gg1, gbt1, gW2, gb2, gW3, gb3,
                                                out_z, out_logits, out_gates);

  // --- mix ---
  mix_kernel<<<128, 256, 0, stream>>>(eo, out_gates, out_mixed);
}

// Round 10
// 433.071 us; speedup vs baseline: 4.6069x; 4.6069x over previous
//
#include <hip/hip_runtime.h>
#include <hip/hip_bf16.h>

// LatentSensorMoE: fused bf16-MFMA expert MLPs + fp32 gate path, single main dispatch.
// B=32768, EIN=128, E=8, experts 128->512->256->128->1 (LN+SiLU per hidden),
// gate: 64->128(LN,SiLU)->128(LN,SiLU); enc 128->64(SiLU)->16; gating 144->128(LN,SiLU)->64(SiLU)->8->softmax.
// Outputs (fp32, concat): mixed[B] | z[B,16] | logits[B,8] | gates[B,8]
//
// R10 = R6 verbatim (best verified PASS, 435us: Xp pack, gate LAST at y==8,
// direct-W gate loads, rcpf silu, h2/h3 alias h1, launch_bounds(256,4))
// + pack_all merge (single pack dispatch — validated by R9's passing run).
// Quarantined (HW evidence): gate LDS W-staging (R9: scratch blowup, 5.4GB HBM),
// direct-X stage-1 + gate-not-last (R7/R8 output corruption), flat f%9 interleave
// (R7), bias-post-loop epilogue + 16-row gate (R3/R4).

typedef __attribute__((ext_vector_type(8))) short bf16x8;   // 8 bf16 = 4 VGPR (MFMA frag)
typedef __attribute__((ext_vector_type(4))) float f32x4;

#define DEV static __device__ __forceinline__

DEV float b2f(unsigned short u){ union { unsigned int i; float f; } x; x.i = ((unsigned int)u) << 16; return x.f; }
DEV unsigned short f2b(float f){
  union { float f; unsigned int i; } x; x.f = f;
  return (unsigned short)((x.i + 0x7fffu + ((x.i >> 16) & 1u)) >> 16);  // RNE
}
DEV unsigned int pk2(float a, float b){
  __hip_bfloat162 h = __float22bfloat162_rn(make_float2(a, b));        // v_cvt_pk_bf16_f32
  union { __hip_bfloat162 h; unsigned int u; } u; u.h = h; return u.u;
}
// silu via fast rcp (v_rcp_f32, ~5 VALU) instead of IEEE div sequence (~10 VALU)
DEV float silu_f(float v){ return v * __builtin_amdgcn_rcpf(1.0f + __expf(-v)); }

// ---------------- pack kernel: X + weights fp32 -> bf16 MFMA fragment layouts ----------------
// A-frag (16x16x32): lane l holds A[m=l&15][k=(l>>4)*8+j], j=0..7
// B-frag:            lane l holds B[k=(l>>4)*8+j][n=l&15]
// Stage s output is written to LDS in permuted k' order; W(s+1) k-dim pre-permuted to match:
//  pi1: col c=(w*128+nt*16+c0) -> k' = w*128 + c0*8 + nt   (nt<8)
//  pi2: col c=(w*64 +nt*16+c0) -> k' = w*64  + c0*4 + nt   (nt<4)
//  pi3: col c=(w*32 +nt*16+c0) -> k' = w*32  + c0*2 + nt   (nt<2)
// blocks [0,256)=W1, [256,768)=W2, [768,896)=W3, [896,900)=w4, [900,2948)=X
__global__ __launch_bounds__(256) void pack_all_kernel(const float* __restrict__ eW1, const float* __restrict__ eW2,
                                                       const float* __restrict__ eW3, const float* __restrict__ eW4,
                                                       const float* __restrict__ X,
                                                       unsigned short* __restrict__ W1p, unsigned short* __restrict__ W2p,
                                                       unsigned short* __restrict__ W3p, float* __restrict__ w4p,
                                                       unsigned short* __restrict__ Xp){
  int b = blockIdx.x;
  if (b < 256){
    int t = b * 256 + threadIdx.x;                 // [0, 65536)
    int l = t & 63, kb = (t >> 6) & 3, ntg = (t >> 8) & 31, e = t >> 13;
    int q = l >> 4, c0 = l & 15, n = ntg * 16 + c0;
    bf16x8 o;
    #pragma unroll
    for (int j = 0; j < 8; j++){ int k = kb*32 + q*8 + j; o[j] = (short)f2b(eW1[((size_t)e*128 + k)*512 + n]); }
    *(bf16x8*)(W1p + (size_t)t * 8) = o;
  } else if (b < 768){
    int t = (b - 256) * 256 + threadIdx.x;         // [0, 131072)
    int l = t & 63, kb = (t >> 6) & 15, ntg = (t >> 10) & 15, e = t >> 14;
    int q = l >> 4, c0 = l & 15, n = ntg * 16 + c0;
    bf16x8 o;
    #pragma unroll
    for (int j = 0; j < 8; j++){
      int kp = kb*32 + q*8 + j;                                        // k' in pi1 space
      int c = (kp >> 7) * 128 + (kp & 7) * 16 + ((kp >> 3) & 15);      // pi1^-1
      o[j] = (short)f2b(eW2[((size_t)e*512 + c)*256 + n]);
    }
    *(bf16x8*)(W2p + (size_t)t * 8) = o;
  } else if (b < 896){
    int t = (b - 768) * 256 + threadIdx.x;         // [0, 32768)
    int l = t & 63, kb = (t >> 6) & 7, ntg = (t >> 9) & 7, e = t >> 12;
    int q = l >> 4, c0 = l & 15, n = ntg * 16 + c0;
    bf16x8 o;
    #pragma unroll
    for (int j = 0; j < 8; j++){
      int kp = kb*32 + q*8 + j;                                        // k' in pi2 space
      int c = (kp >> 6) * 64 + (kp & 3) * 16 + ((kp >> 2) & 15);       // pi2^-1
      o[j] = (short)f2b(eW3[((size_t)e*256 + c)*128 + n]);
    }
    *(bf16x8*)(W3p + (size_t)t * 8) = o;
  } else if (b < 900){
    int t = (b - 896) * 256 + threadIdx.x;
    if (t < 1024){
      int e = t >> 7, kp = t & 127;
      int c = (kp >> 5) * 32 + (kp & 1) * 16 + ((kp >> 1) & 15);       // pi3^-1
      w4p[t] = eW4[e * 128 + c];
    }
  } else {
    int t = (b - 900) * 256 + threadIdx.x;         // [0, 524288)
    int l = t & 63, kb = (t >> 6) & 3, mtg = t >> 8; // mtg: 16-row tile id [0,2048)
    int row = mtg * 16 + (l & 15);
    int k0  = kb * 32 + (l >> 4) * 8;
    const float* src = X + (size_t)row * 128 + k0;
    bf16x8 o;
    #pragma unroll
    for (int j = 0; j < 8; j++) o[j] = (short)f2b(src[j]);
    *(bf16x8*)(Xp + (size_t)t * 8) = o;
  }
}

// ---------------- gate layers (round-2-verified structure, 32 rows/block, direct W loads) ----------------
// N=128 layer: thread tile 4 rows x 4 cols
template<int K, int PIN, int POUT, bool LN>
DEV void glayer128(const float* __restrict__ xs, const float* __restrict__ W, const float* __restrict__ b,
                   const float* __restrict__ g, const float* __restrict__ btv, float* __restrict__ ys, int tid)
{
  const int cg = tid & 31, rg = tid >> 5;
  const int col0 = cg * 4, row0 = rg * 4;
  float4 bv = *(const float4*)(b + col0);
  float acc[4][4];
  #pragma unroll
  for (int r = 0; r < 4; r++){ acc[r][0] = bv.x; acc[r][1] = bv.y; acc[r][2] = bv.z; acc[r][3] = bv.w; }
  for (int k = 0; k < K; k += 4){
    float4 x0 = *(const float4*)(xs + (row0+0)*PIN + k);
    float4 x1 = *(const float4*)(xs + (row0+1)*PIN + k);
    float4 x2 = *(const float4*)(xs + (row0+2)*PIN + k);
    float4 x3 = *(const float4*)(xs + (row0+3)*PIN + k);
    float4 w0 = *(const float4*)(W + (size_t)(k+0)*128 + col0);
    float4 w1 = *(const float4*)(W + (size_t)(k+1)*128 + col0);
    float4 w2 = *(const float4*)(W + (size_t)(k+2)*128 + col0);
    float4 w3 = *(const float4*)(W + (size_t)(k+3)*128 + col0);
    const float xr[4][4] = {{x0.x,x0.y,x0.z,x0.w},{x1.x,x1.y,x1.z,x1.w},{x2.x,x2.y,x2.z,x2.w},{x3.x,x3.y,x3.z,x3.w}};
    const float wr[4][4] = {{w0.x,w0.y,w0.z,w0.w},{w1.x,w1.y,w1.z,w1.w},{w2.x,w2.y,w2.z,w2.w},{w3.x,w3.y,w3.z,w3.w}};
    #pragma unroll
    for (int kk = 0; kk < 4; kk++)
      #pragma unroll
      for (int r = 0; r < 4; r++)
        #pragma unroll
        for (int c = 0; c < 4; c++) acc[r][c] += xr[r][kk] * wr[kk][c];
  }
  float mu[4], rs[4];
  if (LN){
    #pragma unroll
    for (int r = 0; r < 4; r++){
      float s = acc[r][0] + acc[r][1] + acc[r][2] + acc[r][3];
      float qq = acc[r][0]*acc[r][0] + acc[r][1]*acc[r][1] + acc[r][2]*acc[r][2] + acc[r][3]*acc[r][3];
      #pragma unroll
      for (int off = 1; off < 32; off <<= 1){ s += __shfl_xor(s, off, 64); qq += __shfl_xor(qq, off, 64); }
      float m = s * (1.0f/128.0f);
      mu[r] = m; rs[r] = rsqrtf(qq * (1.0f/128.0f) - m*m + 1e-5f);
    }
    float4 gv = *(const float4*)(g + col0);
    float4 tv = *(const float4*)(btv + col0);
    const float gr[4] = {gv.x, gv.y, gv.z, gv.w};
    const float tr[4] = {tv.x, tv.y, tv.z, tv.w};
    #pragma unroll
    for (int r = 0; r < 4; r++)
      #pragma unroll
      for (int c = 0; c < 4; c++) acc[r][c] = (acc[r][c] - mu[r]) * rs[r] * gr[c] + tr[c];
  }
  #pragma unroll
  for (int r = 0; r < 4; r++){
    float4 o;
    o.x = silu_f(acc[r][0]); o.y = silu_f(acc[r][1]); o.z = silu_f(acc[r][2]); o.w = silu_f(acc[r][3]);
    *(float4*)(ys + (row0+r)*POUT + col0) = o;
  }
}

// N=64, SiLU only: thread tile 2 rows x 4 cols
template<int K, int PIN, int POUT>
DEV void glayer64(const float* __restrict__ xs, const float* __restrict__ W, const float* __restrict__ b,
                  float* __restrict__ ys, int tid)
{
  const int cg = tid & 15, rg = tid >> 4;
  const int col0 = cg * 4, row0 = rg * 2;
  float4 bv = *(const float4*)(b + col0);
  float acc[2][4];
  #pragma unroll
  for (int r = 0; r < 2; r++){ acc[r][0] = bv.x; acc[r][1] = bv.y; acc[r][2] = bv.z; acc[r][3] = bv.w; }
  for (int k = 0; k < K; k += 4){
    float4 x0 = *(const float4*)(xs + (row0+0)*PIN + k);
    float4 x1 = *(const float4*)(xs + (row0+1)*PIN + k);
    float4 w0 = *(const float4*)(W + (size_t)(k+0)*64 + col0);
    float4 w1 = *(const float4*)(W + (size_t)(k+1)*64 + col0);
    float4 w2 = *(const float4*)(W + (size_t)(k+2)*64 + col0);
    float4 w3 = *(const float4*)(W + (size_t)(k+3)*64 + col0);
    const float xr[2][4] = {{x0.x,x0.y,x0.z,x0.w},{x1.x,x1.y,x1.z,x1.w}};
    const float wr[4][4] = {{w0.x,w0.y,w0.z,w0.w},{w1.x,w1.y,w1.z,w1.w},{w2.x,w2.y,w2.z,w2.w},{w3.x,w3.y,w3.z,w3.w}};
    #pragma unroll
    for (int kk = 0; kk < 4; kk++)
      #pragma unroll
      for (int r = 0; r < 2; r++)
        #pragma unroll
        for (int c = 0; c < 4; c++) acc[r][c] += xr[r][kk] * wr[kk][c];
  }
  #pragma unroll
  for (int r = 0; r < 2; r++){
    float4 o;
    o.x = silu_f(acc[r][0]); o.y = silu_f(acc[r][1]); o.z = silu_f(acc[r][2]); o.w = silu_f(acc[r][3]);
    *(float4*)(ys + (row0+r)*POUT + col0) = o;
  }
}

DEV void gate_body(unsigned char* smem, int bx, int tid,
                   const float* __restrict__ gf,
                   const float* __restrict__ bW1, const float* __restrict__ bb1, const float* __restrict__ bg1, const float* __restrict__ bbt1,
                   const float* __restrict__ bW2, const float* __restrict__ bb2, const float* __restrict__ bg2, const float* __restrict__ bbt2,
                   const float* __restrict__ encW1, const float* __restrict__ encb1, const float* __restrict__ encW2, const float* __restrict__ encb2,
                   const float* __restrict__ gW1, const float* __restrict__ gb1, const float* __restrict__ gg1v, const float* __restrict__ gbt1,
                   const float* __restrict__ gW2, const float* __restrict__ gb2, const float* __restrict__ gW3, const float* __restrict__ gb3,
                   float* __restrict__ out_z, float* __restrict__ out_logits, float* __restrict__ out_gates)
{
  const int row0 = bx * 32;
  float* xa = (float*)smem;                  // [0, 18944) B : 32*148 floats
  float* xb = (float*)(smem + 18944);        // [18944, 35840) B : 32*132 floats

  // load gate_features [32,64]
  for (int idx = tid; idx < 32*64; idx += 256){
    int r = idx >> 6, k = idx & 63;
    xa[r*148 + k] = gf[(size_t)(row0 + r)*64 + k];
  }
  __syncthreads();
  glayer128<64, 148, 132, true>(xa, bW1, bb1, bg1, bbt1, xb, tid);     // h1 -> xb
  __syncthreads();
  glayer128<128, 132, 148, true>(xb, bW2, bb2, bg2, bbt2, xa, tid);    // h2 -> xa[0..127]
  __syncthreads();
  glayer64<128, 148, 132>(xa, encW1, encb1, xb, tid);                  // enc1 -> xb[0..63]
  __syncthreads();
  { // enc2: xb[32,64] @ encW2[64,16] -> z; write out_z and xa cols 128..143
    int col = tid & 15, rr = tid >> 4;           // rr 0..15 -> rows rr*2, rr*2+1
    float a0 = encb2[col], a1 = a0;
    for (int k = 0; k < 64; k++){
      float wv = encW2[k*16 + col];
      a0 += xb[(rr*2+0)*132 + k] * wv;
      a1 += xb[(rr*2+1)*132 + k] * wv;
    }
    out_z[(size_t)(row0 + rr*2+0)*16 + col] = a0;
    out_z[(size_t)(row0 + rr*2+1)*16 + col] = a1;
    xa[(rr*2+0)*148 + 128 + col] = a0;
    xa[(rr*2+1)*148 + 128 + col] = a1;
  }
  __syncthreads();
  glayer128<144, 148, 132, true>(xa, gW1, gb1, gg1v, gbt1, xb, tid);   // gating h -> xb
  __syncthreads();
  glayer64<128, 132, 148>(xb, gW2, gb2, xa, tid);                      // -> xa[0..63]
  __syncthreads();
  { // g3: xa[32,64] @ gW3[64,8] -> logits; softmax -> gates
    int col = tid & 7, rr = tid >> 3;            // rr 0..31
    float a = gb3[col];
    for (int k = 0; k < 64; k++) a += xa[rr*148 + k] * gW3[k*8 + col];
    out_logits[(size_t)(row0 + rr)*8 + col] = a;
    float m = a;
    m = fmaxf(m, __shfl_xor(m, 1, 64));
    m = fmaxf(m, __shfl_xor(m, 2, 64));
    m = fmaxf(m, __shfl_xor(m, 4, 64));
    float ex = __expf(a - m);
    float s = ex;
    s += __shfl_xor(s, 1, 64); s += __shfl_xor(s, 2, 64); s += __shfl_xor(s, 4, 64);
    out_gates[(size_t)(row0 + rr)*8 + col] = ex / s;
  }
}

// ---------------- main fused dispatch: grid (1024, 9) ----------------
// blockIdx.y < 8 : expert body (32 rows x expert y). blockIdx.y == 8 : gate body
// (dispatches last — the R6-proven schedule).
// LDS: one 35840B carve-out unioned across both bodies -> 4 blocks/CU at (256,4).
#define MFMA_BF16 __builtin_amdgcn_mfma_f32_16x16x32_bf16

__global__ __launch_bounds__(256, 4)
void fused_main(const unsigned short* __restrict__ Xp,
                const unsigned short* __restrict__ W1p,
                const unsigned short* __restrict__ W2p,
                const unsigned short* __restrict__ W3p,
                const float* __restrict__ w4p,
                const float* __restrict__ eb1, const float* __restrict__ eg1, const float* __restrict__ ebt1,
                const float* __restrict__ eb2, const float* __restrict__ eg2, const float* __restrict__ ebt2,
                const float* __restrict__ eb3, const float* __restrict__ eg3, const float* __restrict__ ebt3,
                const float* __restrict__ eb4, float* __restrict__ eo,
                const float* __restrict__ gf,
                const float* __restrict__ bW1, const float* __restrict__ bb1, const float* __restrict__ bg1, const float* __restrict__ bbt1,
                const float* __restrict__ bW2, const float* __restrict__ bb2, const float* __restrict__ bg2, const float* __restrict__ bbt2,
                const float* __restrict__ encW1, const float* __restrict__ encb1, const float* __restrict__ encW2, const float* __restrict__ encb2,
                const float* __restrict__ gW1, const float* __restrict__ gb1, const float* __restrict__ gg1v, const float* __restrict__ gbt1,
                const float* __restrict__ gW2, const float* __restrict__ gb2, const float* __restrict__ gW3, const float* __restrict__ gb3,
                float* __restrict__ out_z, float* __restrict__ out_logits, float* __restrict__ out_gates)
{
  __shared__ __align__(16) unsigned char smem[35840];
  const int tid = threadIdx.x;

  if (blockIdx.y == 8){
    gate_body(smem, blockIdx.x, tid, gf,
              bW1, bb1, bg1, bbt1, bW2, bb2, bg2, bbt2,
              encW1, encb1, encW2, encb2,
              gW1, gb1, gg1v, gbt1, gW2, gb2, gW3, gb3,
              out_z, out_logits, out_gates);
    return;
  }

  const int e = blockIdx.y, bt = blockIdx.x;
  const int w = tid >> 6, l = tid & 63;
  const int q = l >> 4, c0 = l & 15;

  unsigned short* h1 = (unsigned short*)smem;          // [0, 33280) B
  float* redS = (float*)(smem + 33280);                // 128 floats
  float* redQ = (float*)(smem + 33792);                // 128 floats
  float* muS  = (float*)(smem + 34304);                // 32 floats
  float* rsS  = (float*)(smem + 34432);                // 32 floats
  unsigned short* h2 = h1;                 // [0, 16896) B — h1 dead after stage-2 k-loop barrier
  unsigned short* h3 = h1 + 32 * 264;      // [16896, 25600) B — disjoint from h2

  // ===== stage 1: X[32,128] @ W1[128,512], +b (as C-init), LN, SiLU -> h1 (k' = pi1) =====
  {
    float bv[8], gv[8], tv[8];
    #pragma unroll
    for (int nt = 0; nt < 8; nt++){
      int col = w*128 + nt*16 + c0;
      bv[nt] = eb1[e*512 + col]; gv[nt] = eg1[e*512 + col]; tv[nt] = ebt1[e*512 + col];
    }
    f32x4 acc[2][8];
    #pragma unroll
    for (int m = 0; m < 2; m++)
      #pragma unroll
      for (int nt = 0; nt < 8; nt++) acc[m][nt] = (f32x4){bv[nt],bv[nt],bv[nt],bv[nt]};
    #pragma unroll
    for (int kb = 0; kb < 4; kb++){
      bf16x8 a0 = *(const bf16x8*)(Xp + ((size_t)((bt*2 + 0)*4 + kb)*64 + l)*8);
      bf16x8 a1 = *(const bf16x8*)(Xp + ((size_t)((bt*2 + 1)*4 + kb)*64 + l)*8);
      #pragma unroll
      for (int nt = 0; nt < 8; nt++){
        int ntg = w*8 + nt;
        bf16x8 b = *(const bf16x8*)(W1p + ((size_t)((e*32 + ntg)*4 + kb)*64 + l)*8);
        acc[0][nt] = MFMA_BF16(a0, b, acc[0][nt], 0, 0, 0);
        acc[1][nt] = MFMA_BF16(a1, b, acc[1][nt], 0, 0, 0);
      }
    }
    float s[2][4] = {}, sq[2][4] = {};
    #pragma unroll
    for (int nt = 0; nt < 8; nt++)
      #pragma unroll
      for (int m = 0; m < 2; m++)
        #pragma unroll
        for (int r = 0; r < 4; r++){
          float v = acc[m][nt][r];
          s[m][r] += v; sq[m][r] += v*v;
        }
    #pragma unroll
    for (int m = 0; m < 2; m++)
      #pragma unroll
      for (int r = 0; r < 4; r++){
        float a = s[m][r], b = sq[m][r];
        #pragma unroll
        for (int off = 1; off < 16; off <<= 1){ a += __shfl_xor(a, off, 64); b += __shfl_xor(b, off, 64); }
        if (c0 == 0){ int row = m*16 + q*4 + r; redS[row*4 + w] = a; redQ[row*4 + w] = b; }
      }
    __syncthreads();
    if (tid < 32){
      float S = 0.f, Q = 0.f;
      #pragma unroll
      for (int i = 0; i < 4; i++){ S += redS[tid*4 + i]; Q += redQ[tid*4 + i]; }
      float mu = S * (1.0f/512.0f);
      float var = Q * (1.0f/512.0f) - mu*mu;
      muS[tid] = mu; rsS[tid] = rsqrtf(var + 1e-5f);
    }
    __syncthreads();
    #pragma unroll
    for (int m = 0; m < 2; m++)
      #pragma unroll
      for (int r = 0; r < 4; r++){
        int row = m*16 + q*4 + r;
        float mu = muS[row], rs = rsS[row];
        float v[8];
        #pragma unroll
        for (int nt = 0; nt < 8; nt++) v[nt] = silu_f((acc[m][nt][r] - mu) * rs * gv[nt] + tv[nt]);
        uint4 pk;
        pk.x = pk2(v[0], v[1]); pk.y = pk2(v[2], v[3]); pk.z = pk2(v[4], v[5]); pk.w = pk2(v[6], v[7]);
        *(uint4*)(h1 + row*520 + w*128 + c0*8) = pk;   // ds_write_b128, k' = w*128+c0*8+nt
      }
  }
  __syncthreads();

  // ===== stage 2: h1[32,512(pi1)] @ W2p, +b, LN, SiLU -> h2 (k' = pi2, aliases h1) =====
  {
    float bv[4], gv[4], tv[4];
    #pragma unroll
    for (int nt = 0; nt < 4; nt++){
      int col = w*64 + nt*16 + c0;
      bv[nt] = eb2[e*256 + col]; gv[nt] = eg2[e*256 + col]; tv[nt] = ebt2[e*256 + col];
    }
    f32x4 acc[2][4];
    #pragma unroll
    for (int m = 0; m < 2; m++)
      #pragma unroll
      for (int nt = 0; nt < 4; nt++) acc[m][nt] = (f32x4){bv[nt],bv[nt],bv[nt],bv[nt]};
    #pragma unroll 2
    for (int kb = 0; kb < 16; kb++){
      bf16x8 a0 = *(const bf16x8*)(h1 + (0  + c0)*520 + kb*32 + q*8);
      bf16x8 a1 = *(const bf16x8*)(h1 + (16 + c0)*520 + kb*32 + q*8);
      #pragma unroll
      for (int nt = 0; nt < 4; nt++){
        int ntg = w*4 + nt;
        bf16x8 b = *(const bf16x8*)(W2p + ((size_t)((e*16 + ntg)*16 + kb)*64 + l)*8);
        acc[0][nt] = MFMA_BF16(a0, b, acc[0][nt], 0, 0, 0);
        acc[1][nt] = MFMA_BF16(a1, b, acc[1][nt], 0, 0, 0);
      }
    }
    float s[2][4] = {}, sq[2][4] = {};
    #pragma unroll
    for (int nt = 0; nt < 4; nt++)
      #pragma unroll
      for (int m = 0; m < 2; m++)
        #pragma unroll
        for (int r = 0; r < 4; r++){
          float v = acc[m][nt][r];
          s[m][r] += v; sq[m][r] += v*v;
        }
    #pragma unroll
    for (int m = 0; m < 2; m++)
      #pragma unroll
      for (int r = 0; r < 4; r++){
        float a = s[m][r], b = sq[m][r];
        #pragma unroll
        for (int off = 1; off < 16; off <<= 1){ a += __shfl_xor(a, off, 64); b += __shfl_xor(b, off, 64); }
        if (c0 == 0){ int row = m*16 + q*4 + r; redS[row*4 + w] = a; redQ[row*4 + w] = b; }
      }
    __syncthreads();   // all stage-2 k-loop reads of h1 complete here -> h2 may overwrite h1
    if (tid < 32){
      float S = 0.f, Q = 0.f;
      #pragma unroll
      for (int i = 0; i < 4; i++){ S += redS[tid*4 + i]; Q += redQ[tid*4 + i]; }
      float mu = S * (1.0f/256.0f);
      float var = Q * (1.0f/256.0f) - mu*mu;
      muS[tid] = mu; rsS[tid] = rsqrtf(var + 1e-5f);
    }
    __syncthreads();
    #pragma unroll
    for (int m = 0; m < 2; m++)
      #pragma unroll
      for (int r = 0; r < 4; r++){
        int row = m*16 + q*4 + r;
        float mu = muS[row], rs = rsS[row];
        float v[4];
        #pragma unroll
        for (int nt = 0; nt < 4; nt++) v[nt] = silu_f((acc[m][nt][r] - mu) * rs * gv[nt] + tv[nt]);
        uint2 pk; pk.x = pk2(v[0], v[1]); pk.y = pk2(v[2], v[3]);
        *(uint2*)(h2 + row*264 + w*64 + c0*4) = pk;    // ds_write_b64, k' = w*64+c0*4+nt
      }
  }
  __syncthreads();

  // ===== stage 3: h2[32,256(pi2)] @ W3p, +b, LN, SiLU -> h3 (k' = pi3) =====
  {
    float bv[2], gv[2], tv[2];
    #pragma unroll
    for (int nt = 0; nt < 2; nt++){
      int col = w*32 + nt*16 + c0;
      bv[nt] = eb3[e*128 + col]; gv[nt] = eg3[e*128 + col]; tv[nt] = ebt3[e*128 + col];
    }
    f32x4 acc[2][2];
    #pragma unroll
    for (int m = 0; m < 2; m++)
      #pragma unroll
      for (int nt = 0; nt < 2; nt++) acc[m][nt] = (f32x4){bv[nt],bv[nt],bv[nt],bv[nt]};
    #pragma unroll 2
    for (int kb = 0; kb < 8; kb++){
      bf16x8 a0 = *(const bf16x8*)(h2 + (0  + c0)*264 + kb*32 + q*8);
      bf16x8 a1 = *(const bf16x8*)(h2 + (16 + c0)*264 + kb*32 + q*8);
      #pragma unroll
      for (int nt = 0; nt < 2; nt++){
        int ntg = w*2 + nt;
        bf16x8 b = *(const bf16x8*)(W3p + ((size_t)((e*8 + ntg)*8 + kb)*64 + l)*8);
        acc[0][nt] = MFMA_BF16(a0, b, acc[0][nt], 0, 0, 0);
        acc[1][nt] = MFMA_BF16(a1, b, acc[1][nt], 0, 0, 0);
      }
    }
    float s[2][4] = {}, sq[2][4] = {};
    #pragma unroll
    for (int nt = 0; nt < 2; nt++)
      #pragma unroll
      for (int m = 0; m < 2; m++)
        #pragma unroll
        for (int r = 0; r < 4; r++){
          float v = acc[m][nt][r];
          s[m][r] += v; sq[m][r] += v*v;
        }
    #pragma unroll
    for (int m = 0; m < 2; m++)
      #pragma unroll
      for (int r = 0; r < 4; r++){
        float a = s[m][r], b = sq[m][r];
        #pragma unroll
        for (int off = 1; off < 16; off <<= 1){ a += __shfl_xor(a, off, 64); b += __shfl_xor(b, off, 64); }
        if (c0 == 0){ int row = m*16 + q*4 + r; redS[row*4 + w] = a; redQ[row*4 + w] = b; }
      }
    __syncthreads();   // all stage-3 k-loop reads of h2 complete here
    if (tid < 32){
      float S = 0.f, Q = 0.f;
      #pragma unroll
      for (int i = 0; i < 4; i++){ S += redS[tid*4 + i]; Q += redQ[tid*4 + i]; }
      float mu = S * (1.0f/128.0f);
      float var = Q * (1.0f/128.0f) - mu*mu;
      muS[tid] = mu; rsS[tid] = rsqrtf(var + 1e-5f);
    }
    __syncthreads();
    #pragma unroll
    for (int m = 0; m < 2; m++)
      #pragma unroll
      for (int r = 0; r < 4; r++){
        int row = m*16 + q*4 + r;
        float mu = muS[row], rs = rsS[row];
        float v0 = silu_f((acc[m][0][r] - mu) * rs * gv[0] + tv[0]);
        float v1 = silu_f((acc[m][1][r] - mu) * rs * gv[1] + tv[1]);
        *(unsigned int*)(h3 + row*136 + w*32 + c0*2) = pk2(v0, v1);  // ds_write_b32, k' = w*32+c0*2+nt
      }
  }
  __syncthreads();

  // ===== stage 4: h3[32,128(pi3)] . w4p[e] + eb4 -> eo[b, e] =====
  {
    int row = tid >> 3, sub = tid & 7;
    bf16x8 v0 = *(const bf16x8*)(h3 + row*136 + sub*16);
    bf16x8 v1 = *(const bf16x8*)(h3 + row*136 + sub*16 + 8);
    float a = 0.f;
    #pragma unroll
    for (int j = 0; j < 8; j++) a += b2f((unsigned short)v0[j]) * w4p[e*128 + sub*16 + j];
    #pragma unroll
    for (int j = 0; j < 8; j++) a += b2f((unsigned short)v1[j]) * w4p[e*128 + sub*16 + 8 + j];
    a += __shfl_xor(a, 1, 64); a += __shfl_xor(a, 2, 64); a += __shfl_xor(a, 4, 64);
    if (sub == 0) eo[(size_t)(bt*32 + row)*8 + e] = a + eb4[e];
  }
}

// ---------------- final mix: mixed[b] = sum_e eo[b,e]*gates[b,e] ----------------
__global__ __launch_bounds__(256) void mix_kernel(const float* __restrict__ eo, const float* __restrict__ gates,
                                                  float* __restrict__ mixed){
  int t = blockIdx.x * 256 + threadIdx.x;
  if (t < 32768){
    const float4* a = (const float4*)(eo + (size_t)t*8);
    const float4* gg = (const float4*)(gates + (size_t)t*8);
    float4 a0 = a[0], a1 = a[1], g0 = gg[0], g1 = gg[1];
    mixed[t] = a0.x*g0.x + a0.y*g0.y + a0.z*g0.z + a0.w*g0.w
             + a1.x*g1.x + a1.y*g1.y + a1.z*g1.z + a1.w*g1.w;
  }
}

extern "C" void kernel_launch(void* const* d_in, const int* in_sizes, int n_in,
                              void* d_out, int out_size, void* d_ws, size_t ws_size,
                              hipStream_t stream)
{
  if (n_in < 36 || in_sizes[0] != 32768*128 || out_size < 1081344) return;

  const float* expert_features = (const float*)d_in[0];
  const float* gate_features   = (const float*)d_in[1];
  const float* eW1 = (const float*)d_in[2];
  const float* eb1 = (const float*)d_in[3];
  const float* eg1 = (const float*)d_in[4];
  const float* ebt1= (const float*)d_in[5];
  const float* eW2 = (const float*)d_in[6];
  const float* eb2 = (const float*)d_in[7];
  const float* eg2 = (const float*)d_in[8];
  const float* ebt2= (const float*)d_in[9];
  const float* eW3 = (const float*)d_in[10];
  const float* eb3 = (const float*)d_in[11];
  const float* eg3 = (const float*)d_in[12];
  const float* ebt3= (const float*)d_in[13];
  const float* eW4 = (const float*)d_in[14];
  const float* eb4 = (const float*)d_in[15];
  const float* bW1 = (const float*)d_in[16];
  const float* bb1 = (const float*)d_in[17];
  const float* bg1 = (const float*)d_in[18];
  const float* bbt1= (const float*)d_in[19];
  const float* bW2 = (const float*)d_in[20];
  const float* bb2 = (const float*)d_in[21];
  const float* bg2 = (const float*)d_in[22];
  const float* bbt2= (const float*)d_in[23];
  const float* encW1 = (const float*)d_in[24];
  const float* encb1 = (const float*)d_in[25];
  const float* encW2 = (const float*)d_in[26];
  const float* encb2 = (const float*)d_in[27];
  const float* gW1 = (const float*)d_in[28];
  const float* gb1 = (const float*)d_in[29];
  const float* gg1 = (const float*)d_in[30];
  const float* gbt1= (const float*)d_in[31];
  const float* gW2 = (const float*)d_in[32];
  const float* gb2 = (const float*)d_in[33];
  const float* gW3 = (const float*)d_in[34];
  const float* gb3 = (const float*)d_in[35];

  float* out        = (float*)d_out;
  float* out_mixed  = out;                 // [B]
  float* out_z      = out + 32768;         // [B,16]
  float* out_logits = out + 557056;        // [B,8]
  float* out_gates  = out + 819200;        // [B,8]

  char* ws = (char*)d_ws;
  size_t off = 0;
  auto walloc = [&](size_t bytes) -> char* { char* p = ws + off; off += (bytes + 255) & ~(size_t)255; return p; };
  unsigned short* Xp  = (unsigned short*)walloc((size_t)4194304 * 2);  // packed X, bf16
  unsigned short* W1p = (unsigned short*)walloc((size_t)524288  * 2);
  unsigned short* W2p = (unsigned short*)walloc((size_t)1048576 * 2);
  unsigned short* W3p = (unsigned short*)walloc((size_t)262144  * 2);
  float*          w4p = (float*)walloc((size_t)1024 * 4);
  float*          eo  = (float*)walloc((size_t)262144 * 4);            // expert outputs [B,8]
  if (off > ws_size) return;  // workspace too small -> clean failure signal

  // --- pack X + weights (one dispatch; validated in R9) ---
  pack_all_kernel<<<2948, 256, 0, stream>>>(eW1, eW2, eW3, eW4, expert_features,
                                            W1p, W2p, W3p, w4p, Xp);

  // --- experts (y<8) + gate path (y==8, dispatches last — R6-proven schedule) ---
  fused_main<<<dim3(1024, 9), 256, 0, stream>>>(Xp, W1p, W2p, W3p, w4p,
                                                eb1, eg1, ebt1, eb2, eg2, ebt2, eb3, eg3, ebt3,
                                                eb4, eo,
                                                gate_features,
                                                bW1, bb1, bg1, bbt1, bW2, bb2, bg2, bbt2,
                                                encW1, encb1, encW2, encb2,
                                                gW1, gb1, gg1, gbt1, gW2, gb2, gW3, gb3,
                                                out_z, out_logits, out_gates);

  // --- mix ---
  mix_kernel<<<128, 256, 0, stream>>>(eo, out_gates, out_mixed);
}